// Round 3
// baseline (5883.641 us; speedup 1.0000x reference)
//
#include <hip/hip_runtime.h>
#include <hip/hip_cooperative_groups.h>

namespace cg = cooperative_groups;

#define IDX_BITS 20
#define IDX_MASK ((1u << IDX_BITS) - 1)
#define NBLOCKS 1024
#define NTHREADS 256
#define MAXPASS 500
#define SC_CAP 256

typedef unsigned long long u64;

struct Ctx {
  const int* __restrict__ neighs;
  const float* __restrict__ hier;
  const int* __restrict__ row_splits;
  int V, K, nseg;
  ulonglong2* pa;      // [V] .x = pri (smaller = earlier), .y = assign_pri (min grabber)
  u64* bmin0;          // [V] ping-pong blocked-min arrays
  u64* bmin1;
  u64* centre_pri;     // [V]
  int* centre_v;       // [V]
  int* rank_of;        // [V]
  int* cnt;            // [0..2] any-survivor flags (rot mod 3), [3] centre count, [8+s] seg counts
  int* out_sel;
  int* out_rs;
  int* out_gg;
};

__global__ void __launch_bounds__(NTHREADS, 4) cluster_kernel(Ctx c) {
  cg::grid_group grid = cg::this_grid();
  const int tid = blockIdx.x * blockDim.x + threadIdx.x;
  const int nthr = gridDim.x * blockDim.x;
  const int W = nthr >> 6;          // total waves
  const int gw = tid >> 6;          // global wave id
  const int lane = threadIdx.x & 63;
  const int V = c.V, K = c.K;
  u64* bmin[2] = { c.bmin0, c.bmin1 };

  __shared__ int sc_cnt;
  __shared__ int sc_base;
  __shared__ int sc_list[SC_CAP];
  __shared__ u64 shp[NTHREADS];

  if (threadIdx.x == 0) sc_cnt = 0;

  // ---------- pass 0: compute pri, everyone blocks (scatter-only, no gathers) ----------
  for (int u = gw; u < V; u += W) {
    unsigned int bits = __float_as_uint(c.hier[u]);   // hier in [0,1): flip bits -> descending
    int seg = 0;
    for (int s = 1; s < c.nseg; ++s) seg += (u >= c.row_splits[s]);
    u64 pu = ((u64)seg << (IDX_BITS + 32)) | ((u64)(~bits) << IDX_BITS) | (unsigned)u;
    if (lane == 0) c.pa[u].x = pu;
    const int* row = c.neighs + (size_t)u * K;
    for (int j = lane; j < K; j += 64) {
      int w = row[j];
      if (w != u) atomicMin(&c.bmin0[w], pu);  // unconditional: larger-pri blockers are inert
    }
  }
  __threadfence();
  grid.sync();

  // ---------- fused decide+block passes: ONE grid.sync per round ----------
  int p = 1;
  while (true) {
    u64* rb = bmin[(p - 1) & 1];
    u64* wb = bmin[p & 1];
    bool any_surv = false;

    for (int u = gw; u < V; u += W) {
      ulonglong2 pav = c.pa[u];                 // 16B broadcast load: pri + assign_pri
      u64 pu = pav.x;
      // dead OR already-decided centre (centres self-grab -> y == pu exactly;
      // pris are unique so y == pu can only come from the self-grab).
      // Round-2 bug was `<` here: centres stayed "alive" forever.
      if (pav.y <= pu) continue;
      u64 bm = rb[u];
      const int* row = c.neighs + (size_t)u * K;
      if (bm > pu) {
        // centre: no live earlier in-neighbour remains -> grab (fire-and-forget scatters)
        for (int j = lane; j < K; j += 64)
          atomicMin(&c.pa[row[j]].y, pu);       // includes self: marks this centre done
        if (lane == 0) {
          int s = atomicAdd(&sc_cnt, 1);
          if (s < SC_CAP) sc_list[s] = u;
          else {                                // overflow fallback
            int slot = atomicAdd(&c.cnt[3], 1);
            c.centre_v[slot] = u;
            c.centre_pri[slot] = pu;
            atomicAdd(&c.cnt[8 + (int)(pu >> (IDX_BITS + 32))], 1);
          }
        }
      } else {
        // survivor: reset own slot for round p+1's writers, re-block later neighbours
        any_surv = true;
        if (lane == 0) rb[u] = ~0ull;
        for (int j = lane; j < K; j += 64) {
          int w = row[j];
          if (w != u) atomicMin(&wb[w], pu);
        }
      }
    }
    if (any_surv && lane == 0) c.cnt[p % 3] = 1;   // racy same-value store, fine
    if (tid == 0) c.cnt[(p + 1) % 3] = 0;          // pre-zero next pass's flag

    // flush block-local centre staging (1 global atomicAdd per block per pass)
    __syncthreads();
    int nloc = min(sc_cnt, SC_CAP);
    if (threadIdx.x == 0 && nloc > 0) sc_base = atomicAdd(&c.cnt[3], nloc);
    __syncthreads();
    for (int i = threadIdx.x; i < nloc; i += NTHREADS) {
      int v = sc_list[i];
      u64 pv = c.pa[v].x;
      c.centre_v[sc_base + i] = v;
      c.centre_pri[sc_base + i] = pv;
      atomicAdd(&c.cnt[8 + (int)(pv >> (IDX_BITS + 32))], 1);
    }
    __syncthreads();
    if (threadIdx.x == 0) sc_cnt = 0;

    __threadfence();
    grid.sync();
    int flag = c.cnt[p % 3];
    ++p;
    if (!flag || p > MAXPASS) break;
  }

  // ---------- centre ranks: O(nC^2) LDS-tiled counting (nC ~ thousands) ----------
  int nC = c.cnt[3];
  {
    bool have = tid < nC;
    u64 mypri = have ? c.centre_pri[tid] : 0;
    int myv = have ? c.centre_v[tid] : 0;
    int myrank = 0;
    for (int cs = 0; cs < nC; cs += NTHREADS) {
      int j = cs + threadIdx.x;
      shp[threadIdx.x] = (j < nC) ? c.centre_pri[j] : ~0ull;
      __syncthreads();
      int lim = min(NTHREADS, nC - cs);
      for (int t = 0; t < lim; ++t) myrank += (shp[t] < mypri) ? 1 : 0;
      __syncthreads();
    }
    if (have) {
      c.out_sel[myrank] = myv;     // rank among centre pris == cumsum position in order
      c.rank_of[myv] = myrank;
    }
  }
  if (tid == 0) {
    int run = 0;
    c.out_rs[0] = 0;
    for (int s = 0; s < c.nseg; ++s) { run += c.cnt[8 + s]; c.out_rs[s + 1] = run; }
  }
  __threadfence();
  grid.sync();

  // ---------- ggather ----------
  for (int v = tid; v < V; v += nthr) {
    ulonglong2 pav = c.pa[v];
    int ctr = (pav.y < pav.x) ? (int)(pav.y & IDX_MASK) : v;
    c.out_gg[v] = c.rank_of[ctr];
  }
}

extern "C" void kernel_launch(void* const* d_in, const int* in_sizes, int n_in,
                              void* d_out, int out_size, void* d_ws, size_t ws_size,
                              hipStream_t stream) {
  Ctx c;
  c.neighs = (const int*)d_in[0];
  c.hier = (const float*)d_in[1];
  c.row_splits = (const int*)d_in[2];
  c.V = in_sizes[1];
  c.K = in_sizes[0] / c.V;
  c.nseg = in_sizes[2] - 1;

  char* pm = (char*)d_ws;
  const size_t V = (size_t)c.V;
  c.pa = (ulonglong2*)pm;      pm += V * 16;
  c.bmin0 = (u64*)pm;          pm += V * 8;
  c.bmin1 = (u64*)pm;          pm += V * 8;
  // everything above must start as all-ones (0xFF); pa.x overwritten in pass 0
  size_t ff_bytes = V * 32;
  c.centre_pri = (u64*)pm;     pm += V * 8;
  c.centre_v = (int*)pm;       pm += V * 4;
  c.rank_of = (int*)pm;        pm += V * 4;
  c.cnt = (int*)pm;            pm += 64 * 4;

  int* out = (int*)d_out;
  c.out_sel = out;
  c.out_rs = out + c.V;
  c.out_gg = out + c.V + c.nseg + 1;

  hipMemsetAsync(d_ws, 0xFF, ff_bytes, stream);          // pa + bmin0 + bmin1 -> ~0
  hipMemsetAsync((void*)c.cnt, 0, 64 * 4, stream);       // flags, centre count, seg counts
  hipMemsetAsync((void*)c.out_sel, 0xFF, V * 4, stream); // sel padding = -1

  void* args[] = { &c };
  hipLaunchCooperativeKernel((void*)cluster_kernel, dim3(NBLOCKS), dim3(NTHREADS),
                             args, 0, stream);
}